// Round 7
// baseline (2126.298 us; speedup 1.0000x reference)
//
#include <hip/hip_runtime.h>
#include <hip/hip_fp16.h>
#include <math.h>

#define NN 100000
#define KK 16
#define CI 128
#define NG 512

typedef short bf16x8 __attribute__((ext_vector_type(8)));   // 8 bf16 in 4 VGPRs
typedef float f32x4 __attribute__((ext_vector_type(4)));

// ---------------- ws layout (bytes) ----------------
#define OFF_XW      0ULL                  // fp16 [100000][512] packed gates (ch*4+g), bias folded
#define OFF_XR      102400000ULL          // fp32 [100000][128] = x@lin_r^T + lin_l_b
#define OFF_WTI     153600000ULL          // fp32 [128 k][512 p] packed W_ih^T
#define OFF_BP      153862144ULL          // fp32 [512] packed bias
#define OFF_WHH_HI  153864192ULL          // bf16 frag-linear [32 mtile][4 ks][64 lane][8]
#define OFF_WHH_LO  153995264ULL
#define OFF_LIN_HI  154126336ULL          // bf16 frag-linear [8 mtile][4 ks][64 lane][8]
#define OFF_LIN_LO  154159104ULL
#define OFF_LRT     154191872ULL          // fp32 [128 k][128 j] lin_r^T
#define WS_NEED     154257408ULL

// fallback (round-1) ws layout
#define WT_OFF 0
#define WT_SZ  (256 * 512)
#define LT_OFF (WT_SZ)
#define LT_SZ  (256 * 128)
#define BP_OFF (WT_SZ + LT_SZ)
#define BP_SZ  512
#define WS_FLOATS (WT_SZ + LT_SZ + BP_SZ)

__device__ __forceinline__ float fast_rcp(float x) { return __builtin_amdgcn_rcpf(x); }
// sigm(x) = 1/(1+e^-x); inf-safe: x<<0 -> exp=inf -> rcp=0; x>>0 -> exp=0 -> 1
__device__ __forceinline__ float sigm(float x) {
    return fast_rcp(1.f + __builtin_amdgcn_exp2f(x * -1.4426950408889634f));
}
// tanh(x) = 1 - 2/(1+e^{2x}); inf-safe both directions, no clamp needed
__device__ __forceinline__ float tanh_f(float x) {
    float e = __builtin_amdgcn_exp2f(x * 2.885390081777927f);
    return fmaf(-2.f, fast_rcp(1.f + e), 1.f);
}
__device__ __forceinline__ ushort f2bf(float x) {
    unsigned u = __float_as_uint(x);
    unsigned r = u + 0x7fffu + ((u >> 16) & 1u);
    return (ushort)(r >> 16);
}
__device__ __forceinline__ void bsplit(float x, ushort& hi, ushort& lo) {
    unsigned u = __float_as_uint(x);
    unsigned r = u + 0x7fffu + ((u >> 16) & 1u);
    hi = (ushort)(r >> 16);
    float hv = __uint_as_float(r & 0xffff0000u);
    lo = f2bf(x - hv);
}

// ================= prep0: weight repack =================
__global__ void prep0_kernel(const float* __restrict__ W_ih, const float* __restrict__ W_hh,
                             const float* __restrict__ b_ih, const float* __restrict__ b_hh,
                             const float* __restrict__ lin_l_w, const float* __restrict__ lin_r_w,
                             char* __restrict__ wsb) {
    int i = blockIdx.x * 256 + threadIdx.x;
    float* WTI = (float*)(wsb + OFF_WTI);
    float* BP  = (float*)(wsb + OFF_BP);
    ushort* WHI = (ushort*)(wsb + OFF_WHH_HI);
    ushort* WLO = (ushort*)(wsb + OFF_WHH_LO);
    ushort* LHI = (ushort*)(wsb + OFF_LIN_HI);
    ushort* LLO = (ushort*)(wsb + OFF_LIN_LO);
    float* LRT = (float*)(wsb + OFF_LRT);
    if (i < 65536) {
        int k = i >> 9, p = i & 511;
        WTI[i] = W_ih[((p & 3) * 128 + (p >> 2)) * 128 + k];
    } else if (i < 66048) {
        int p = i - 65536;
        int row = (p & 3) * 128 + (p >> 2);
        BP[p] = b_ih[row] + b_hh[row];
    } else if (i < 131584) {
        int e = i - 66048;
        int frag = e >> 9, lane = (e >> 3) & 63, j = e & 7;
        int mt = frag >> 2, ks = frag & 3;
        int p = mt * 16 + (lane & 15);
        int k = ks * 32 + ((lane >> 4) & 3) * 8 + j;
        float v = W_hh[((p & 3) * 128 + (p >> 2)) * 128 + k];
        ushort hi, lo; bsplit(v, hi, lo);
        WHI[e] = hi; WLO[e] = lo;
    } else if (i < 147968) {
        int e = i - 131584;
        int frag = e >> 9, lane = (e >> 3) & 63, j = e & 7;
        int mt = frag >> 2, ks = frag & 3;
        int row = mt * 16 + (lane & 15);
        int k = ks * 32 + ((lane >> 4) & 3) * 8 + j;
        float v = lin_l_w[row * 128 + k];
        ushort hi, lo; bsplit(v, hi, lo);
        LHI[e] = hi; LLO[e] = lo;
    } else if (i < 164352) {
        int e = i - 147968;
        int k = e >> 7, j = e & 127;
        LRT[e] = lin_r_w[j * 128 + k];
    }
}

// ================= prep_xw: XW = x @ W_ih^T + b (fp16, packed) =================
__global__ __launch_bounds__(256, 2)
void prep_xw_kernel(const float* __restrict__ node_feats, char* __restrict__ wsb) {
    const float* __restrict__ WTI = (const float*)(wsb + OFF_WTI);
    const float* __restrict__ BP  = (const float*)(wsb + OFF_BP);
    __half2* __restrict__ XW = (__half2*)(wsb + OFF_XW);
    __shared__ __align__(16) float xs[32][128];
    const int tid = threadIdx.x;
    const int n0 = blockIdx.x * 32;
    {
        int m = tid >> 3, sub = tid & 7;
        const float4* srow = (const float4*)(node_feats + (size_t)(n0 + m) * CI);
        float4* drow = (float4*)(&xs[m][0]);
        #pragma unroll
        for (int it = 0; it < 4; ++it) drow[sub + it * 8] = srow[sub + it * 8];
    }
    __syncthreads();
    float acc0[32], acc1[32];
    #pragma unroll
    for (int m = 0; m < 32; ++m) { acc0[m] = 0.f; acc1[m] = 0.f; }
    const float* wb = WTI + tid * 2;
    float2 w0 = *(const float2*)(wb + 0 * NG);
    float2 w1 = *(const float2*)(wb + 1 * NG);
    float2 w2 = *(const float2*)(wb + 2 * NG);
    float2 w3 = *(const float2*)(wb + 3 * NG);
    #pragma unroll 1
    for (int c = 0; c < 128; c += 4) {
        const int cn = (c + 4) & 127;
        float2 u0 = *(const float2*)(wb + (cn + 0) * NG);
        float2 u1 = *(const float2*)(wb + (cn + 1) * NG);
        float2 u2 = *(const float2*)(wb + (cn + 2) * NG);
        float2 u3 = *(const float2*)(wb + (cn + 3) * NG);
        #pragma unroll
        for (int m = 0; m < 32; ++m) {
            float4 iv = *(const float4*)(&xs[m][c]);
            acc0[m] = fmaf(iv.x, w0.x, acc0[m]); acc1[m] = fmaf(iv.x, w0.y, acc1[m]);
            acc0[m] = fmaf(iv.y, w1.x, acc0[m]); acc1[m] = fmaf(iv.y, w1.y, acc1[m]);
            acc0[m] = fmaf(iv.z, w2.x, acc0[m]); acc1[m] = fmaf(iv.z, w2.y, acc1[m]);
            acc0[m] = fmaf(iv.w, w3.x, acc0[m]); acc1[m] = fmaf(iv.w, w3.y, acc1[m]);
        }
        w0 = u0; w1 = u1; w2 = u2; w3 = u3;
    }
    const float b0 = BP[tid * 2], b1 = BP[tid * 2 + 1];
    #pragma unroll
    for (int m = 0; m < 32; ++m) {
        __half2 hv = __floats2half2_rn(acc0[m] + b0, acc1[m] + b1);
        XW[(size_t)(n0 + m) * 256 + tid] = hv;
    }
}

// ================= prep_xr: XR = x @ lin_r^T + lin_l_b (fp32) =================
__global__ __launch_bounds__(256, 2)
void prep_xr_kernel(const float* __restrict__ node_feats, const float* __restrict__ lin_l_b,
                    char* __restrict__ wsb) {
    const float* __restrict__ LRT = (const float*)(wsb + OFF_LRT);
    float* __restrict__ XR = (float*)(wsb + OFF_XR);
    __shared__ __align__(16) float xs[32][128];
    const int tid = threadIdx.x;
    const int n0 = blockIdx.x * 32;
    {
        int m = tid >> 3, sub = tid & 7;
        const float4* srow = (const float4*)(node_feats + (size_t)(n0 + m) * CI);
        float4* drow = (float4*)(&xs[m][0]);
        #pragma unroll
        for (int it = 0; it < 4; ++it) drow[sub + it * 8] = srow[sub + it * 8];
    }
    __syncthreads();
    const int j = tid & 127, mh = tid >> 7;
    float facc[16];
    #pragma unroll
    for (int mm = 0; mm < 16; ++mm) facc[mm] = 0.f;
    const float* lb_ = LRT + j;
    #pragma unroll 1
    for (int c = 0; c < 128; c += 4) {
        float l0 = lb_[(c + 0) * 128];
        float l1 = lb_[(c + 1) * 128];
        float l2 = lb_[(c + 2) * 128];
        float l3 = lb_[(c + 3) * 128];
        #pragma unroll
        for (int mm = 0; mm < 16; ++mm) {
            const float4 iv = *(const float4*)(&xs[mh * 16 + mm][c]);
            facc[mm] = fmaf(iv.x, l0, fmaf(iv.y, l1, fmaf(iv.z, l2, fmaf(iv.w, l3, facc[mm]))));
        }
    }
    const float lbv = lin_l_b[j];
    #pragma unroll
    for (int mm = 0; mm < 16; ++mm)
        XR[(size_t)(n0 + mh * 16 + mm) * 128 + j] = facc[mm] + lbv;
}

// ================= main: fused LSTM recurrence + SAGE epilogue (MFMA) =================
// 64 nodes/block, 8 waves. H double-buffered (1 barrier/step), t=0 peeled,
// XW gather issued one step ahead (post-consumption) to hide HBM latency.
// launch_bounds(512, 1): VGPR cap 256 (was 128 -> ~810 MB/dispatch scratch spills, r6).
// 8 waves/CU occupancy is unchanged at <=256 VGPR (m69), so the extra regs are free.
__global__ __launch_bounds__(512, 1)
void lstm_main_kernel(const int* __restrict__ srcg, const char* __restrict__ wsb,
                      float* __restrict__ out) {
    const ushort* __restrict__ xw  = (const ushort*)(wsb + OFF_XW);
    const float*  __restrict__ xr  = (const float*)(wsb + OFF_XR);
    const ushort* __restrict__ whh_hi = (const ushort*)(wsb + OFF_WHH_HI);
    const ushort* __restrict__ whh_lo = (const ushort*)(wsb + OFF_WHH_LO);
    const ushort* __restrict__ lin_hi = (const ushort*)(wsb + OFF_LIN_HI);
    const ushort* __restrict__ lin_lo = (const ushort*)(wsb + OFF_LIN_LO);

    __shared__ __align__(16) ushort Hhi[2][8192];   // [buf][node*128+ch] bf16, XOR-swizzled
    __shared__ __align__(16) ushort Hlo[2][8192];
    __shared__ int srcb[1024];                      // [t][node]

    const int tid = threadIdx.x;
    const int n0 = blockIdx.x * 64;
    const int wid = tid >> 6, lane = tid & 63;
    const int l15 = lane & 15, l4 = lane >> 4;
    const int swz = (l15 & 7) << 4;

    for (int i = tid; i < 1024; i += 512) {
        int n = i & 63, t = i >> 6;
        int gn = n0 + n; if (gn > NN - 1) gn = NN - 1;
        srcb[t * 64 + n] = srcg[gn * 16 + t];
    }
    __syncthreads();

    float cst[4][4];
    #pragma unroll
    for (int mt = 0; mt < 4; ++mt)
        #pragma unroll
        for (int nt = 0; nt < 4; ++nt) cst[mt][nt] = 0.f;

    uint2 xwv[4][4];
    // gather for step tp into xwv (addresses depend only on srcb -> pure prefetch)
    auto gather = [&](int tp) {
        #pragma unroll
        for (int nt = 0; nt < 4; ++nt) {
            const int sn = srcb[tp * 64 + nt * 16 + l15];
            const ushort* rowp = xw + (size_t)sn * 512 + (wid * 16 + l4) * 4;
            #pragma unroll
            for (int mt = 0; mt < 4; ++mt)
                xwv[mt][nt] = *(const uint2*)(rowp + mt * 16);
        }
    };
    // LSTM cell for one step: gates = acc + xwv; writes h to Hbuf[cb]
    auto cell = [&](f32x4 (&acc)[4][4], int cb) {
        char* Whi_ = (char*)Hhi[cb];
        char* Wlo_ = (char*)Hlo[cb];
        #pragma unroll
        for (int mt = 0; mt < 4; ++mt) {
            #pragma unroll
            for (int nt = 0; nt < 4; ++nt) {
                uint2 v = xwv[mt][nt];
                float2 f01 = __half22float2(*(__half2*)&v.x);
                float2 f23 = __half22float2(*(__half2*)&v.y);
                float gi = acc[mt][nt][0] + f01.x;
                float gf = acc[mt][nt][1] + f01.y;
                float gg = acc[mt][nt][2] + f23.x;
                float go = acc[mt][nt][3] + f23.y;
                float cn_ = fmaf(sigm(gi), tanh_f(gg), sigm(gf) * cst[mt][nt]);
                cst[mt][nt] = cn_;
                float hn = sigm(go) * tanh_f(cn_);
                ushort hb, lb; bsplit(hn, hb, lb);
                const int wb = ((nt * 16 + l15) * 256 + (wid * 16 + mt * 4 + l4) * 2) ^ swz;
                *(ushort*)(Whi_ + wb) = hb;
                *(ushort*)(Wlo_ + wb) = lb;
            }
        }
    };

    // ---- t = 0: h0 = 0 -> gates = XW only; no MFMA, no H init ----
    gather(0);
    {
        f32x4 z[4][4];
        #pragma unroll
        for (int mt = 0; mt < 4; ++mt)
            #pragma unroll
            for (int nt = 0; nt < 4; ++nt) z[mt][nt] = (f32x4){0.f, 0.f, 0.f, 0.f};
        cell(z, 0);
    }
    gather(1);
    __syncthreads();

    #pragma unroll 1
    for (int t = 1; t < KK; ++t) {
        const char* HRhi = (const char*)Hhi[(t + 1) & 1];   // read buf (t-1)&1
        const char* HRlo = (const char*)Hlo[(t + 1) & 1];
        f32x4 acc[4][4];
        #pragma unroll
        for (int mt = 0; mt < 4; ++mt)
            #pragma unroll
            for (int nt = 0; nt < 4; ++nt) acc[mt][nt] = (f32x4){0.f, 0.f, 0.f, 0.f};

        #pragma unroll
        for (int ks = 0; ks < 4; ++ks) {
            bf16x8 bh[4], bl[4];
            #pragma unroll
            for (int nt = 0; nt < 4; ++nt) {
                const int bo = ((nt * 16 + l15) * 256 + ks * 64 + l4 * 16) ^ swz;
                bh[nt] = *(const bf16x8*)(HRhi + bo);
                bl[nt] = *(const bf16x8*)(HRlo + bo);
            }
            #pragma unroll
            for (int mt = 0; mt < 4; ++mt) {
                const int fo = (((wid * 4 + mt) * 4 + ks) << 9) + lane * 8;
                bf16x8 ah = *(const bf16x8*)(whh_hi + fo);
                bf16x8 al = *(const bf16x8*)(whh_lo + fo);
                #pragma unroll
                for (int nt = 0; nt < 4; ++nt) {
                    acc[mt][nt] = __builtin_amdgcn_mfma_f32_16x16x32_bf16(ah, bh[nt], acc[mt][nt], 0, 0, 0);
                    acc[mt][nt] = __builtin_amdgcn_mfma_f32_16x16x32_bf16(ah, bl[nt], acc[mt][nt], 0, 0, 0);
                    acc[mt][nt] = __builtin_amdgcn_mfma_f32_16x16x32_bf16(al, bh[nt], acc[mt][nt], 0, 0, 0);
                }
            }
        }
        cell(acc, t & 1);
        if (t < KK - 1) gather(t + 1);   // prefetch next step (full-step latency cover)
        __syncthreads();
    }

    // ---- epilogue: out = relu(XR + h_last @ lin_l^T), h_last in buf 1 ----
    f32x4 acc2[4];
    #pragma unroll
    for (int nt = 0; nt < 4; ++nt) acc2[nt] = (f32x4){0.f, 0.f, 0.f, 0.f};
    #pragma unroll
    for (int ks = 0; ks < 4; ++ks) {
        bf16x8 bh[4], bl[4];
        #pragma unroll
        for (int nt = 0; nt < 4; ++nt) {
            const int bo = ((nt * 16 + l15) * 256 + ks * 64 + l4 * 16) ^ swz;
            bh[nt] = *(const bf16x8*)((const char*)Hhi[1] + bo);
            bl[nt] = *(const bf16x8*)((const char*)Hlo[1] + bo);
        }
        const int fo = ((wid * 4 + ks) << 9) + lane * 8;
        bf16x8 ah = *(const bf16x8*)(lin_hi + fo);
        bf16x8 al = *(const bf16x8*)(lin_lo + fo);
        #pragma unroll
        for (int nt = 0; nt < 4; ++nt) {
            acc2[nt] = __builtin_amdgcn_mfma_f32_16x16x32_bf16(ah, bh[nt], acc2[nt], 0, 0, 0);
            acc2[nt] = __builtin_amdgcn_mfma_f32_16x16x32_bf16(ah, bl[nt], acc2[nt], 0, 0, 0);
            acc2[nt] = __builtin_amdgcn_mfma_f32_16x16x32_bf16(al, bh[nt], acc2[nt], 0, 0, 0);
        }
    }
    #pragma unroll
    for (int nt = 0; nt < 4; ++nt) {
        const int nl = nt * 16 + l15;
        const int gn = n0 + nl;
        if (gn < NN) {
            const size_t base = (size_t)gn * 128 + wid * 16 + l4 * 4;
            float4 xv = *(const float4*)(xr + base);
            float4 ov;
            ov.x = fmaxf(acc2[nt][0] + xv.x, 0.f);
            ov.y = fmaxf(acc2[nt][1] + xv.y, 0.f);
            ov.z = fmaxf(acc2[nt][2] + xv.z, 0.f);
            ov.w = fmaxf(acc2[nt][3] + xv.w, 0.f);
            *(float4*)(out + base) = ov;
        }
    }
}

// ===================== round-1 fallback path (small ws) =====================
__global__ void prep_kernel(const float* __restrict__ W_ih, const float* __restrict__ W_hh,
                            const float* __restrict__ b_ih, const float* __restrict__ b_hh,
                            const float* __restrict__ lin_l_w, const float* __restrict__ lin_r_w,
                            float* __restrict__ ws) {
    int i = blockIdx.x * 256 + threadIdx.x;
    if (i < WT_SZ) {
        int cc = i >> 9, jj = i & 511;
        int ch = jj >> 2, g = jj & 3;
        int row = g * 128 + ch;
        ws[WT_OFF + i] = (cc < 128) ? W_ih[row * 128 + cc] : W_hh[row * 128 + (cc - 128)];
    } else if (i < WT_SZ + LT_SZ) {
        int k = i - WT_SZ;
        int cc = k >> 7, j = k & 127;
        ws[i] = (cc < 128) ? lin_r_w[j * 128 + cc] : lin_l_w[j * 128 + (cc - 128)];
    } else if (i < WS_FLOATS) {
        int j = i - (WT_SZ + LT_SZ);
        int ch = j >> 2, g = j & 3;
        ws[i] = b_ih[g * 128 + ch] + b_hh[g * 128 + ch];
    }
}

__global__ __launch_bounds__(256, 2)
void gnn_lstm_kernel(const float* __restrict__ node_feats,
                     const int* __restrict__ src,
                     const float* __restrict__ lin_l_b,
                     const float* __restrict__ ws,
                     float* __restrict__ out) {
    const float* __restrict__ WT = ws + WT_OFF;
    const float* __restrict__ LT = ws + LT_OFF;
    const float* __restrict__ BP = ws + BP_OFF;
    __shared__ __align__(16) float xh[32][256];
    const int tid = threadIdx.x;
    const int n0 = blockIdx.x * 32;
    {
        int ch = tid >> 1;
        #pragma unroll
        for (int m = 0; m < 32; ++m) xh[m][128 + ch] = 0.f;
    }
    float creg[32];
    #pragma unroll
    for (int m = 0; m < 32; ++m) creg[m] = 0.f;
    const float4 bpv = *(const float4*)(BP + ((tid >> 1) << 2));
    const bool odd = (tid & 1);
    const float* wb = WT + (tid << 1);
    for (int t = 0; t < KK; ++t) {
        {
            int m = tid >> 3, sub = tid & 7;
            int sidx = src[(n0 + m) * KK + t];
            const float4* srow = (const float4*)(node_feats + (size_t)sidx * CI);
            float4* drow = (float4*)(&xh[m][0]);
            #pragma unroll
            for (int it = 0; it < 4; ++it) drow[sub + it * 8] = srow[sub + it * 8];
        }
        __syncthreads();
        float acc0[32], acc1[32];
        #pragma unroll
        for (int m = 0; m < 32; ++m) { acc0[m] = 0.f; acc1[m] = 0.f; }
        float2 w0 = *(const float2*)(wb + 0 * NG);
        float2 w1 = *(const float2*)(wb + 1 * NG);
        float2 w2 = *(const float2*)(wb + 2 * NG);
        float2 w3 = *(const float2*)(wb + 3 * NG);
        #pragma unroll 1
        for (int c = 0; c < 256; c += 4) {
            const int cn = (c + 4) & 255;
            float2 u0 = *(const float2*)(wb + (cn + 0) * NG);
            float2 u1 = *(const float2*)(wb + (cn + 1) * NG);
            float2 u2 = *(const float2*)(wb + (cn + 2) * NG);
            float2 u3 = *(const float2*)(wb + (cn + 3) * NG);
            #pragma unroll
            for (int m = 0; m < 32; ++m) {
                float4 iv = *(const float4*)(&xh[m][c]);
                acc0[m] = fmaf(iv.x, w0.x, acc0[m]); acc1[m] = fmaf(iv.x, w0.y, acc1[m]);
                acc0[m] = fmaf(iv.y, w1.x, acc0[m]); acc1[m] = fmaf(iv.y, w1.y, acc1[m]);
                acc0[m] = fmaf(iv.z, w2.x, acc0[m]); acc1[m] = fmaf(iv.z, w2.y, acc1[m]);
                acc0[m] = fmaf(iv.w, w3.x, acc0[m]); acc1[m] = fmaf(iv.w, w3.y, acc1[m]);
            }
            w0 = u0; w1 = u1; w2 = u2; w3 = u3;
        }
        __syncthreads();
        const int ch = tid >> 1;
        #pragma unroll
        for (int m = 0; m < 32; ++m) {
            float a0 = acc0[m], a1 = acc1[m];
            float p0 = __shfl_xor(a0, 1);
            float p1 = __shfl_xor(a1, 1);
            float gi = (odd ? p0 : a0) + bpv.x;
            float gf = (odd ? p1 : a1) + bpv.y;
            float gg = (odd ? a0 : p0) + bpv.z;
            float go = (odd ? a1 : p1) + bpv.w;
            float cn_ = sigm(gf) * creg[m] + sigm(gi) * tanh_f(gg);
            creg[m] = cn_;
            float hn = sigm(go) * tanh_f(cn_);
            xh[m][128 + ch] = hn;
        }
    }
    {
        int m = tid >> 3, sub = tid & 7;
        const float4* srow = (const float4*)(node_feats + (size_t)(n0 + m) * CI);
        float4* drow = (float4*)(&xh[m][0]);
        #pragma unroll
        for (int it = 0; it < 4; ++it) drow[sub + it * 8] = srow[sub + it * 8];
    }
    __syncthreads();
    {
        const int jo = tid & 127;
        const int mh = tid >> 7;
        float facc[16];
        #pragma unroll
        for (int mm = 0; mm < 16; ++mm) facc[mm] = 0.f;
        const float* lb_ = LT + jo;
        #pragma unroll 1
        for (int c = 0; c < 256; c += 4) {
            float l0 = lb_[(c + 0) * 128];
            float l1 = lb_[(c + 1) * 128];
            float l2 = lb_[(c + 2) * 128];
            float l3 = lb_[(c + 3) * 128];
            #pragma unroll
            for (int mm = 0; mm < 16; ++mm) {
                const float4 iv = *(const float4*)(&xh[mh * 16 + mm][c]);
                facc[mm] = fmaf(iv.x, l0, fmaf(iv.y, l1, fmaf(iv.z, l2, fmaf(iv.w, l3, facc[mm]))));
            }
        }
        const float lbv = lin_l_b[jo];
        #pragma unroll
        for (int mm = 0; mm < 16; ++mm) {
            float v = facc[mm] + lbv;
            out[(size_t)(n0 + mh * 16 + mm) * CI + jo] = fmaxf(v, 0.f);
        }
    }
}

extern "C" void kernel_launch(void* const* d_in, const int* in_sizes, int n_in,
                              void* d_out, int out_size, void* d_ws, size_t ws_size,
                              hipStream_t stream) {
    const float* node_feats = (const float*)d_in[0];
    const int*   edge_index = (const int*)d_in[1];
    const float* W_ih    = (const float*)d_in[2];
    const float* W_hh    = (const float*)d_in[3];
    const float* b_ih    = (const float*)d_in[4];
    const float* b_hh    = (const float*)d_in[5];
    const float* lin_l_w = (const float*)d_in[6];
    const float* lin_l_b = (const float*)d_in[7];
    const float* lin_r_w = (const float*)d_in[8];
    const int* src = edge_index;
    float* outp = (float*)d_out;

    if (ws_size >= WS_NEED) {
        char* wsb = (char*)d_ws;
        hipLaunchKernelGGL(prep0_kernel, dim3(642), dim3(256), 0, stream,
                           W_ih, W_hh, b_ih, b_hh, lin_l_w, lin_r_w, wsb);
        hipLaunchKernelGGL(prep_xw_kernel, dim3(3125), dim3(256), 0, stream, node_feats, wsb);
        hipLaunchKernelGGL(prep_xr_kernel, dim3(3125), dim3(256), 0, stream, node_feats, lin_l_b, wsb);
        hipLaunchKernelGGL(lstm_main_kernel, dim3((NN + 63) / 64), dim3(512), 0, stream,
                           src, wsb, outp);
    } else {
        float* ws = (float*)d_ws;
        hipLaunchKernelGGL(prep_kernel, dim3((WS_FLOATS + 255) / 256), dim3(256), 0, stream,
                           W_ih, W_hh, b_ih, b_hh, lin_l_w, lin_r_w, ws);
        hipLaunchKernelGGL(gnn_lstm_kernel, dim3(NN / 32), dim3(256), 0, stream,
                           node_feats, src, lin_l_b, ws, outp);
    }
}

// Round 8
// 1661.146 us; speedup vs baseline: 1.2800x; 1.2800x over previous
//
#include <hip/hip_runtime.h>
#include <hip/hip_fp16.h>
#include <math.h>

#define NN 100000
#define KK 16
#define CI 128
#define NG 512

typedef short bf16x8 __attribute__((ext_vector_type(8)));   // 8 bf16 in 4 VGPRs
typedef float f32x4 __attribute__((ext_vector_type(4)));

// ---------------- ws layout (bytes) ----------------
#define OFF_XW      0ULL                  // fp16 [100000][512] packed gates (ch*4+g), bias folded
#define OFF_XR      102400000ULL          // fp32 [100000][128] = x@lin_r^T + lin_l_b
#define OFF_WTI     153600000ULL          // fp32 [128 k][512 p] packed W_ih^T
#define OFF_BP      153862144ULL          // fp32 [512] packed bias
#define OFF_WHH_HI  153864192ULL          // bf16 frag-linear [32 mtile][4 ks][64 lane][8]
#define OFF_WHH_LO  153995264ULL
#define OFF_LIN_HI  154126336ULL          // bf16 frag-linear [8 mtile][4 ks][64 lane][8]
#define OFF_LIN_LO  154159104ULL
#define OFF_LRT     154191872ULL          // fp32 [128 k][128 j] lin_r^T
#define WS_NEED     154257408ULL

// fallback (round-1) ws layout
#define WT_OFF 0
#define WT_SZ  (256 * 512)
#define LT_OFF (WT_SZ)
#define LT_SZ  (256 * 128)
#define BP_OFF (WT_SZ + LT_SZ)
#define BP_SZ  512
#define WS_FLOATS (WT_SZ + LT_SZ + BP_SZ)

__device__ __forceinline__ float fast_rcp(float x) { return __builtin_amdgcn_rcpf(x); }
// sigm(x) = 1/(1+e^-x); inf-safe: x<<0 -> exp=inf -> rcp=0; x>>0 -> exp=0 -> 1
__device__ __forceinline__ float sigm(float x) {
    return fast_rcp(1.f + __builtin_amdgcn_exp2f(x * -1.4426950408889634f));
}
// tanh(x) = 1 - 2/(1+e^{2x}); inf-safe both directions, no clamp needed
__device__ __forceinline__ float tanh_f(float x) {
    float e = __builtin_amdgcn_exp2f(x * 2.885390081777927f);
    return fmaf(-2.f, fast_rcp(1.f + e), 1.f);
}
__device__ __forceinline__ ushort f2bf(float x) {
    unsigned u = __float_as_uint(x);
    unsigned r = u + 0x7fffu + ((u >> 16) & 1u);
    return (ushort)(r >> 16);
}
__device__ __forceinline__ void bsplit(float x, ushort& hi, ushort& lo) {
    unsigned u = __float_as_uint(x);
    unsigned r = u + 0x7fffu + ((u >> 16) & 1u);
    hi = (ushort)(r >> 16);
    float hv = __uint_as_float(r & 0xffff0000u);
    lo = f2bf(x - hv);
}

// ================= prep0: weight repack =================
__global__ void prep0_kernel(const float* __restrict__ W_ih, const float* __restrict__ W_hh,
                             const float* __restrict__ b_ih, const float* __restrict__ b_hh,
                             const float* __restrict__ lin_l_w, const float* __restrict__ lin_r_w,
                             char* __restrict__ wsb) {
    int i = blockIdx.x * 256 + threadIdx.x;
    float* WTI = (float*)(wsb + OFF_WTI);
    float* BP  = (float*)(wsb + OFF_BP);
    ushort* WHI = (ushort*)(wsb + OFF_WHH_HI);
    ushort* WLO = (ushort*)(wsb + OFF_WHH_LO);
    ushort* LHI = (ushort*)(wsb + OFF_LIN_HI);
    ushort* LLO = (ushort*)(wsb + OFF_LIN_LO);
    float* LRT = (float*)(wsb + OFF_LRT);
    if (i < 65536) {
        int k = i >> 9, p = i & 511;
        WTI[i] = W_ih[((p & 3) * 128 + (p >> 2)) * 128 + k];
    } else if (i < 66048) {
        int p = i - 65536;
        int row = (p & 3) * 128 + (p >> 2);
        BP[p] = b_ih[row] + b_hh[row];
    } else if (i < 131584) {
        int e = i - 66048;
        int frag = e >> 9, lane = (e >> 3) & 63, j = e & 7;
        int mt = frag >> 2, ks = frag & 3;
        int p = mt * 16 + (lane & 15);
        int k = ks * 32 + ((lane >> 4) & 3) * 8 + j;
        float v = W_hh[((p & 3) * 128 + (p >> 2)) * 128 + k];
        ushort hi, lo; bsplit(v, hi, lo);
        WHI[e] = hi; WLO[e] = lo;
    } else if (i < 147968) {
        int e = i - 131584;
        int frag = e >> 9, lane = (e >> 3) & 63, j = e & 7;
        int mt = frag >> 2, ks = frag & 3;
        int row = mt * 16 + (lane & 15);
        int k = ks * 32 + ((lane >> 4) & 3) * 8 + j;
        float v = lin_l_w[row * 128 + k];
        ushort hi, lo; bsplit(v, hi, lo);
        LHI[e] = hi; LLO[e] = lo;
    } else if (i < 164352) {
        int e = i - 147968;
        int k = e >> 7, j = e & 127;
        LRT[e] = lin_r_w[j * 128 + k];
    }
}

// ================= prep_xw: XW = x @ W_ih^T + b (fp16, packed) =================
__global__ __launch_bounds__(256, 2)
void prep_xw_kernel(const float* __restrict__ node_feats, char* __restrict__ wsb) {
    const float* __restrict__ WTI = (const float*)(wsb + OFF_WTI);
    const float* __restrict__ BP  = (const float*)(wsb + OFF_BP);
    __half2* __restrict__ XW = (__half2*)(wsb + OFF_XW);
    __shared__ __align__(16) float xs[32][128];
    const int tid = threadIdx.x;
    const int n0 = blockIdx.x * 32;
    {
        int m = tid >> 3, sub = tid & 7;
        const float4* srow = (const float4*)(node_feats + (size_t)(n0 + m) * CI);
        float4* drow = (float4*)(&xs[m][0]);
        #pragma unroll
        for (int it = 0; it < 4; ++it) drow[sub + it * 8] = srow[sub + it * 8];
    }
    __syncthreads();
    float acc0[32], acc1[32];
    #pragma unroll
    for (int m = 0; m < 32; ++m) { acc0[m] = 0.f; acc1[m] = 0.f; }
    const float* wb = WTI + tid * 2;
    float2 w0 = *(const float2*)(wb + 0 * NG);
    float2 w1 = *(const float2*)(wb + 1 * NG);
    float2 w2 = *(const float2*)(wb + 2 * NG);
    float2 w3 = *(const float2*)(wb + 3 * NG);
    #pragma unroll 1
    for (int c = 0; c < 128; c += 4) {
        const int cn = (c + 4) & 127;
        float2 u0 = *(const float2*)(wb + (cn + 0) * NG);
        float2 u1 = *(const float2*)(wb + (cn + 1) * NG);
        float2 u2 = *(const float2*)(wb + (cn + 2) * NG);
        float2 u3 = *(const float2*)(wb + (cn + 3) * NG);
        #pragma unroll
        for (int m = 0; m < 32; ++m) {
            float4 iv = *(const float4*)(&xs[m][c]);
            acc0[m] = fmaf(iv.x, w0.x, acc0[m]); acc1[m] = fmaf(iv.x, w0.y, acc1[m]);
            acc0[m] = fmaf(iv.y, w1.x, acc0[m]); acc1[m] = fmaf(iv.y, w1.y, acc1[m]);
            acc0[m] = fmaf(iv.z, w2.x, acc0[m]); acc1[m] = fmaf(iv.z, w2.y, acc1[m]);
            acc0[m] = fmaf(iv.w, w3.x, acc0[m]); acc1[m] = fmaf(iv.w, w3.y, acc1[m]);
        }
        w0 = u0; w1 = u1; w2 = u2; w3 = u3;
    }
    const float b0 = BP[tid * 2], b1 = BP[tid * 2 + 1];
    #pragma unroll
    for (int m = 0; m < 32; ++m) {
        __half2 hv = __floats2half2_rn(acc0[m] + b0, acc1[m] + b1);
        XW[(size_t)(n0 + m) * 256 + tid] = hv;
    }
}

// ================= prep_xr: XR = x @ lin_r^T + lin_l_b (fp32) =================
__global__ __launch_bounds__(256, 2)
void prep_xr_kernel(const float* __restrict__ node_feats, const float* __restrict__ lin_l_b,
                    char* __restrict__ wsb) {
    const float* __restrict__ LRT = (const float*)(wsb + OFF_LRT);
    float* __restrict__ XR = (float*)(wsb + OFF_XR);
    __shared__ __align__(16) float xs[32][128];
    const int tid = threadIdx.x;
    const int n0 = blockIdx.x * 32;
    {
        int m = tid >> 3, sub = tid & 7;
        const float4* srow = (const float4*)(node_feats + (size_t)(n0 + m) * CI);
        float4* drow = (float4*)(&xs[m][0]);
        #pragma unroll
        for (int it = 0; it < 4; ++it) drow[sub + it * 8] = srow[sub + it * 8];
    }
    __syncthreads();
    const int j = tid & 127, mh = tid >> 7;
    float facc[16];
    #pragma unroll
    for (int mm = 0; mm < 16; ++mm) facc[mm] = 0.f;
    const float* lb_ = LRT + j;
    #pragma unroll 1
    for (int c = 0; c < 128; c += 4) {
        float l0 = lb_[(c + 0) * 128];
        float l1 = lb_[(c + 1) * 128];
        float l2 = lb_[(c + 2) * 128];
        float l3 = lb_[(c + 3) * 128];
        #pragma unroll
        for (int mm = 0; mm < 16; ++mm) {
            const float4 iv = *(const float4*)(&xs[mh * 16 + mm][c]);
            facc[mm] = fmaf(iv.x, l0, fmaf(iv.y, l1, fmaf(iv.z, l2, fmaf(iv.w, l3, facc[mm]))));
        }
    }
    const float lbv = lin_l_b[j];
    #pragma unroll
    for (int mm = 0; mm < 16; ++mm)
        XR[(size_t)(n0 + mh * 16 + mm) * 128 + j] = facc[mm] + lbv;
}

// ================= main: fused LSTM recurrence + SAGE epilogue (MFMA) =================
// 64 nodes/block, 8 waves, H double-buffered, 1 barrier/step, t=0 peeled.
// r8 restructure: per-HALF GEMM+cell (mt pairs {0,1},{2,3}) so acc liveness is
// [2][4]=32 regs (not 64) and xwv is gathered just-in-time per half (16 regs).
// Each acc[mt][nt] holds the complete i,f,g,o of one (node,channel) -> cell can
// consume per half. sched_barrier(0) between halves pins the split so regalloc
// can't re-merge live ranges. Goal: fit 128-VGPR cap, zero scratch
// (r6/r7: 810 MB/dispatch spill traffic at 190-reg demand).
__global__ __launch_bounds__(512, 2)
void lstm_main_kernel(const int* __restrict__ srcg, const char* __restrict__ wsb,
                      float* __restrict__ out) {
    const ushort* __restrict__ xw  = (const ushort*)(wsb + OFF_XW);
    const float*  __restrict__ xr  = (const float*)(wsb + OFF_XR);
    const ushort* __restrict__ whh_hi = (const ushort*)(wsb + OFF_WHH_HI);
    const ushort* __restrict__ whh_lo = (const ushort*)(wsb + OFF_WHH_LO);
    const ushort* __restrict__ lin_hi = (const ushort*)(wsb + OFF_LIN_HI);
    const ushort* __restrict__ lin_lo = (const ushort*)(wsb + OFF_LIN_LO);

    __shared__ __align__(16) ushort Hhi[2][8192];   // [buf][node*128+ch] bf16, XOR-swizzled
    __shared__ __align__(16) ushort Hlo[2][8192];
    __shared__ int srcb[1024];                      // [t][node]

    const int tid = threadIdx.x;
    const int n0 = blockIdx.x * 64;
    const int wid = tid >> 6, lane = tid & 63;
    const int l15 = lane & 15, l4 = lane >> 4;
    const int swz = (l15 & 7) << 4;

    for (int i = tid; i < 1024; i += 512) {
        int n = i & 63, t = i >> 6;
        int gn = n0 + n; if (gn > NN - 1) gn = NN - 1;
        srcb[t * 64 + n] = srcg[gn * 16 + t];
    }
    __syncthreads();

    float cst[4][4];
    #pragma unroll
    for (int mt = 0; mt < 4; ++mt)
        #pragma unroll
        for (int nt = 0; nt < 4; ++nt) cst[mt][nt] = 0.f;

    // ---- t = 0 peel: h0 = 0 -> gates = XW only; writes H(0) to buf 0 ----
    #pragma unroll
    for (int h = 0; h < 2; ++h) {
        #pragma unroll
        for (int nt = 0; nt < 4; ++nt) {
            const int sn = srcb[0 * 64 + nt * 16 + l15];
            const ushort* rowp = xw + (size_t)sn * 512;
            #pragma unroll
            for (int mp = 0; mp < 2; ++mp) {
                const int mtg = h * 2 + mp;
                uint2 v = *(const uint2*)(rowp + (wid * 16 + mtg * 4 + l4) * 4);
                float2 f01 = __half22float2(*(__half2*)&v.x);
                float2 f23 = __half22float2(*(__half2*)&v.y);
                float cn_ = sigm(f01.x) * tanh_f(f23.x);   // i*g (f-term: c=0)
                cst[mtg][nt] = cn_;
                float hn = sigm(f23.y) * tanh_f(cn_);
                ushort hb, lb; bsplit(hn, hb, lb);
                const int wb = ((nt * 16 + l15) * 256 + (wid * 16 + mtg * 4 + l4) * 2) ^ swz;
                *(ushort*)((char*)Hhi[0] + wb) = hb;
                *(ushort*)((char*)Hlo[0] + wb) = lb;
            }
        }
    }
    __syncthreads();

    #pragma unroll 1
    for (int t = 1; t < KK; ++t) {
        const char* HRhi = (const char*)Hhi[(t + 1) & 1];   // read buf (t-1)&1
        const char* HRlo = (const char*)Hlo[(t + 1) & 1];
        char* HWhi = (char*)Hhi[t & 1];
        char* HWlo = (char*)Hlo[t & 1];

        #pragma unroll
        for (int h = 0; h < 2; ++h) {
            __builtin_amdgcn_sched_barrier(0);   // pin half split (keep liveness low)
            // --- JIT gather of this half's XW (8 loads, hidden under MFMAs) ---
            uint2 xwv[2][4];
            #pragma unroll
            for (int nt = 0; nt < 4; ++nt) {
                const int sn = srcb[t * 64 + nt * 16 + l15];
                const ushort* rowp = xw + (size_t)sn * 512 + (wid * 16 + l4) * 4;
                #pragma unroll
                for (int mp = 0; mp < 2; ++mp)
                    xwv[mp][nt] = *(const uint2*)(rowp + (h * 2 + mp) * 16);
            }
            // --- GEMM for this half: acc[2][4] ---
            f32x4 acc[2][4];
            #pragma unroll
            for (int mp = 0; mp < 2; ++mp)
                #pragma unroll
                for (int nt = 0; nt < 4; ++nt) acc[mp][nt] = (f32x4){0.f, 0.f, 0.f, 0.f};

            #pragma unroll
            for (int ks = 0; ks < 4; ++ks) {
                bf16x8 ah[2], al[2];
                #pragma unroll
                for (int mp = 0; mp < 2; ++mp) {
                    const int fo = (((wid * 4 + h * 2 + mp) * 4 + ks) << 9) + lane * 8;
                    ah[mp] = *(const bf16x8*)(whh_hi + fo);
                    al[mp] = *(const bf16x8*)(whh_lo + fo);
                }
                #pragma unroll
                for (int nt = 0; nt < 4; ++nt) {
                    const int bo = ((nt * 16 + l15) * 256 + ks * 64 + l4 * 16) ^ swz;
                    bf16x8 bh = *(const bf16x8*)(HRhi + bo);
                    bf16x8 bl = *(const bf16x8*)(HRlo + bo);
                    #pragma unroll
                    for (int mp = 0; mp < 2; ++mp) {
                        acc[mp][nt] = __builtin_amdgcn_mfma_f32_16x16x32_bf16(ah[mp], bh, acc[mp][nt], 0, 0, 0);
                        acc[mp][nt] = __builtin_amdgcn_mfma_f32_16x16x32_bf16(ah[mp], bl, acc[mp][nt], 0, 0, 0);
                        acc[mp][nt] = __builtin_amdgcn_mfma_f32_16x16x32_bf16(al[mp], bh, acc[mp][nt], 0, 0, 0);
                    }
                }
            }
            // --- cell for this half's channels; writes H(t) to write-buf ---
            #pragma unroll
            for (int mp = 0; mp < 2; ++mp) {
                const int mtg = h * 2 + mp;
                #pragma unroll
                for (int nt = 0; nt < 4; ++nt) {
                    uint2 v = xwv[mp][nt];
                    float2 f01 = __half22float2(*(__half2*)&v.x);
                    float2 f23 = __half22float2(*(__half2*)&v.y);
                    float gi = acc[mp][nt][0] + f01.x;
                    float gf = acc[mp][nt][1] + f01.y;
                    float gg = acc[mp][nt][2] + f23.x;
                    float go = acc[mp][nt][3] + f23.y;
                    float cn_ = fmaf(sigm(gi), tanh_f(gg), sigm(gf) * cst[mtg][nt]);
                    cst[mtg][nt] = cn_;
                    float hn = sigm(go) * tanh_f(cn_);
                    ushort hb, lb; bsplit(hn, hb, lb);
                    const int wb = ((nt * 16 + l15) * 256 + (wid * 16 + mtg * 4 + l4) * 2) ^ swz;
                    *(ushort*)(HWhi + wb) = hb;
                    *(ushort*)(HWlo + wb) = lb;
                }
            }
        }
        __syncthreads();   // H(t) complete; H(t-1) free for overwrite next step
    }

    // ---- epilogue: out = relu(XR + h_last @ lin_l^T), h_last in buf 1 ----
    f32x4 acc2[4];
    #pragma unroll
    for (int nt = 0; nt < 4; ++nt) acc2[nt] = (f32x4){0.f, 0.f, 0.f, 0.f};
    #pragma unroll
    for (int ks = 0; ks < 4; ++ks) {
        const int fo = ((wid * 4 + ks) << 9) + lane * 8;
        bf16x8 ah = *(const bf16x8*)(lin_hi + fo);
        bf16x8 al = *(const bf16x8*)(lin_lo + fo);
        #pragma unroll
        for (int nt = 0; nt < 4; ++nt) {
            const int bo = ((nt * 16 + l15) * 256 + ks * 64 + l4 * 16) ^ swz;
            bf16x8 bh = *(const bf16x8*)((const char*)Hhi[1] + bo);
            bf16x8 bl = *(const bf16x8*)((const char*)Hlo[1] + bo);
            acc2[nt] = __builtin_amdgcn_mfma_f32_16x16x32_bf16(ah, bh, acc2[nt], 0, 0, 0);
            acc2[nt] = __builtin_amdgcn_mfma_f32_16x16x32_bf16(ah, bl, acc2[nt], 0, 0, 0);
            acc2[nt] = __builtin_amdgcn_mfma_f32_16x16x32_bf16(al, bh, acc2[nt], 0, 0, 0);
        }
    }
    #pragma unroll
    for (int nt = 0; nt < 4; ++nt) {
        const int nl = nt * 16 + l15;
        const int gn = n0 + nl;
        if (gn < NN) {
            const size_t base = (size_t)gn * 128 + wid * 16 + l4 * 4;
            float4 xv = *(const float4*)(xr + base);
            float4 ov;
            ov.x = fmaxf(acc2[nt][0] + xv.x, 0.f);
            ov.y = fmaxf(acc2[nt][1] + xv.y, 0.f);
            ov.z = fmaxf(acc2[nt][2] + xv.z, 0.f);
            ov.w = fmaxf(acc2[nt][3] + xv.w, 0.f);
            *(float4*)(out + base) = ov;
        }
    }
}

// ===================== round-1 fallback path (small ws) =====================
__global__ void prep_kernel(const float* __restrict__ W_ih, const float* __restrict__ W_hh,
                            const float* __restrict__ b_ih, const float* __restrict__ b_hh,
                            const float* __restrict__ lin_l_w, const float* __restrict__ lin_r_w,
                            float* __restrict__ ws) {
    int i = blockIdx.x * 256 + threadIdx.x;
    if (i < WT_SZ) {
        int cc = i >> 9, jj = i & 511;
        int ch = jj >> 2, g = jj & 3;
        int row = g * 128 + ch;
        ws[WT_OFF + i] = (cc < 128) ? W_ih[row * 128 + cc] : W_hh[row * 128 + (cc - 128)];
    } else if (i < WT_SZ + LT_SZ) {
        int k = i - WT_SZ;
        int cc = k >> 7, j = k & 127;
        ws[i] = (cc < 128) ? lin_r_w[j * 128 + cc] : lin_l_w[j * 128 + (cc - 128)];
    } else if (i < WS_FLOATS) {
        int j = i - (WT_SZ + LT_SZ);
        int ch = j >> 2, g = j & 3;
        ws[i] = b_ih[g * 128 + ch] + b_hh[g * 128 + ch];
    }
}

__global__ __launch_bounds__(256, 2)
void gnn_lstm_kernel(const float* __restrict__ node_feats,
                     const int* __restrict__ src,
                     const float* __restrict__ lin_l_b,
                     const float* __restrict__ ws,
                     float* __restrict__ out) {
    const float* __restrict__ WT = ws + WT_OFF;
    const float* __restrict__ LT = ws + LT_OFF;
    const float* __restrict__ BP = ws + BP_OFF;
    __shared__ __align__(16) float xh[32][256];
    const int tid = threadIdx.x;
    const int n0 = blockIdx.x * 32;
    {
        int ch = tid >> 1;
        #pragma unroll
        for (int m = 0; m < 32; ++m) xh[m][128 + ch] = 0.f;
    }
    float creg[32];
    #pragma unroll
    for (int m = 0; m < 32; ++m) creg[m] = 0.f;
    const float4 bpv = *(const float4*)(BP + ((tid >> 1) << 2));
    const bool odd = (tid & 1);
    const float* wb = WT + (tid << 1);
    for (int t = 0; t < KK; ++t) {
        {
            int m = tid >> 3, sub = tid & 7;
            int sidx = src[(n0 + m) * KK + t];
            const float4* srow = (const float4*)(node_feats + (size_t)sidx * CI);
            float4* drow = (float4*)(&xh[m][0]);
            #pragma unroll
            for (int it = 0; it < 4; ++it) drow[sub + it * 8] = srow[sub + it * 8];
        }
        __syncthreads();
        float acc0[32], acc1[32];
        #pragma unroll
        for (int m = 0; m < 32; ++m) { acc0[m] = 0.f; acc1[m] = 0.f; }
        float2 w0 = *(const float2*)(wb + 0 * NG);
        float2 w1 = *(const float2*)(wb + 1 * NG);
        float2 w2 = *(const float2*)(wb + 2 * NG);
        float2 w3 = *(const float2*)(wb + 3 * NG);
        #pragma unroll 1
        for (int c = 0; c < 256; c += 4) {
            const int cn = (c + 4) & 255;
            float2 u0 = *(const float2*)(wb + (cn + 0) * NG);
            float2 u1 = *(const float2*)(wb + (cn + 1) * NG);
            float2 u2 = *(const float2*)(wb + (cn + 2) * NG);
            float2 u3 = *(const float2*)(wb + (cn + 3) * NG);
            #pragma unroll
            for (int m = 0; m < 32; ++m) {
                float4 iv = *(const float4*)(&xh[m][c]);
                acc0[m] = fmaf(iv.x, w0.x, acc0[m]); acc1[m] = fmaf(iv.x, w0.y, acc1[m]);
                acc0[m] = fmaf(iv.y, w1.x, acc0[m]); acc1[m] = fmaf(iv.y, w1.y, acc1[m]);
                acc0[m] = fmaf(iv.z, w2.x, acc0[m]); acc1[m] = fmaf(iv.z, w2.y, acc1[m]);
                acc0[m] = fmaf(iv.w, w3.x, acc0[m]); acc1[m] = fmaf(iv.w, w3.y, acc1[m]);
            }
            w0 = u0; w1 = u1; w2 = u2; w3 = u3;
        }
        __syncthreads();
        const int ch = tid >> 1;
        #pragma unroll
        for (int m = 0; m < 32; ++m) {
            float a0 = acc0[m], a1 = acc1[m];
            float p0 = __shfl_xor(a0, 1);
            float p1 = __shfl_xor(a1, 1);
            float gi = (odd ? p0 : a0) + bpv.x;
            float gf = (odd ? p1 : a1) + bpv.y;
            float gg = (odd ? a0 : p0) + bpv.z;
            float go = (odd ? a1 : p1) + bpv.w;
            float cn_ = sigm(gf) * creg[m] + sigm(gi) * tanh_f(gg);
            creg[m] = cn_;
            float hn = sigm(go) * tanh_f(cn_);
            xh[m][128 + ch] = hn;
        }
    }
    {
        int m = tid >> 3, sub = tid & 7;
        const float4* srow = (const float4*)(node_feats + (size_t)(n0 + m) * CI);
        float4* drow = (float4*)(&xh[m][0]);
        #pragma unroll
        for (int it = 0; it < 4; ++it) drow[sub + it * 8] = srow[sub + it * 8];
    }
    __syncthreads();
    {
        const int jo = tid & 127;
        const int mh = tid >> 7;
        float facc[16];
        #pragma unroll
        for (int mm = 0; mm < 16; ++mm) facc[mm] = 0.f;
        const float* lb_ = LT + jo;
        #pragma unroll 1
        for (int c = 0; c < 256; c += 4) {
            float l0 = lb_[(c + 0) * 128];
            float l1 = lb_[(c + 1) * 128];
            float l2 = lb_[(c + 2) * 128];
            float l3 = lb_[(c + 3) * 128];
            #pragma unroll
            for (int mm = 0; mm < 16; ++mm) {
                const float4 iv = *(const float4*)(&xh[mh * 16 + mm][c]);
                facc[mm] = fmaf(iv.x, l0, fmaf(iv.y, l1, fmaf(iv.z, l2, fmaf(iv.w, l3, facc[mm]))));
            }
        }
        const float lbv = lin_l_b[jo];
        #pragma unroll
        for (int mm = 0; mm < 16; ++mm) {
            float v = facc[mm] + lbv;
            out[(size_t)(n0 + mh * 16 + mm) * CI + jo] = fmaxf(v, 0.f);
        }
    }
}

extern "C" void kernel_launch(void* const* d_in, const int* in_sizes, int n_in,
                              void* d_out, int out_size, void* d_ws, size_t ws_size,
                              hipStream_t stream) {
    const float* node_feats = (const float*)d_in[0];
    const int*   edge_index = (const int*)d_in[1];
    const float* W_ih    = (const float*)d_in[2];
    const float* W_hh    = (const float*)d_in[3];
    const float* b_ih    = (const float*)d_in[4];
    const float* b_hh    = (const float*)d_in[5];
    const float* lin_l_w = (const float*)d_in[6];
    const float* lin_l_b = (const float*)d_in[7];
    const float* lin_r_w = (const float*)d_in[8];
    const int* src = edge_index;
    float* outp = (float*)d_out;

    if (ws_size >= WS_NEED) {
        char* wsb = (char*)d_ws;
        hipLaunchKernelGGL(prep0_kernel, dim3(642), dim3(256), 0, stream,
                           W_ih, W_hh, b_ih, b_hh, lin_l_w, lin_r_w, wsb);
        hipLaunchKernelGGL(prep_xw_kernel, dim3(3125), dim3(256), 0, stream, node_feats, wsb);
        hipLaunchKernelGGL(prep_xr_kernel, dim3(3125), dim3(256), 0, stream, node_feats, lin_l_b, wsb);
        hipLaunchKernelGGL(lstm_main_kernel, dim3((NN + 63) / 64), dim3(512), 0, stream,
                           src, wsb, outp);
    } else {
        float* ws = (float*)d_ws;
        hipLaunchKernelGGL(prep_kernel, dim3((WS_FLOATS + 255) / 256), dim3(256), 0, stream,
                           W_ih, W_hh, b_ih, b_hh, lin_l_w, lin_r_w, ws);
        hipLaunchKernelGGL(gnn_lstm_kernel, dim3(NN / 32), dim3(256), 0, stream,
                           node_feats, src, lin_l_b, ws, outp);
    }
}

// Round 9
// 1034.498 us; speedup vs baseline: 2.0554x; 1.6058x over previous
//
#include <hip/hip_runtime.h>
#include <hip/hip_fp16.h>
#include <math.h>

#define NN 100000
#define KK 16
#define CI 128
#define NG 512

typedef _Float16 f16x8 __attribute__((ext_vector_type(8)));  // 8 fp16 in 4 VGPRs
typedef float f32x4 __attribute__((ext_vector_type(4)));

// ---------------- ws layout (bytes) ----------------
#define OFF_XW      0ULL                  // fp16 [100000][512] packed gates (ch*4+g), bias folded
#define OFF_XR      102400000ULL          // fp32 [100000][128] = x@lin_r^T + lin_l_b
#define OFF_WTI     153600000ULL          // fp32 [128 k][512 p] packed W_ih^T
#define OFF_BP      153862144ULL          // fp32 [512] packed bias
#define OFF_WHH_HI  153864192ULL          // fp16 frag-linear [32 mtile][4 ks][64 lane][8]
#define OFF_WHH_LO  153995264ULL          // fp16 residual (W - hi)
#define OFF_LIN_HI  154126336ULL          // fp16 frag-linear [8 mtile][4 ks][64 lane][8]
#define OFF_LIN_LO  154159104ULL
#define OFF_LRT     154191872ULL          // fp32 [128 k][128 j] lin_r^T
#define WS_NEED     154257408ULL

// fallback (round-1) ws layout
#define WT_OFF 0
#define WT_SZ  (256 * 512)
#define LT_OFF (WT_SZ)
#define LT_SZ  (256 * 128)
#define BP_OFF (WT_SZ + LT_SZ)
#define BP_SZ  512
#define WS_FLOATS (WT_SZ + LT_SZ + BP_SZ)

__device__ __forceinline__ float fast_rcp(float x) { return __builtin_amdgcn_rcpf(x); }
// sigm(x) = 1/(1+e^-x); inf-safe: x<<0 -> exp=inf -> rcp=0; x>>0 -> exp=0 -> 1
__device__ __forceinline__ float sigm(float x) {
    return fast_rcp(1.f + __builtin_amdgcn_exp2f(x * -1.4426950408889634f));
}
// tanh(x) = 1 - 2/(1+e^{2x}); inf-safe both directions, no clamp needed
__device__ __forceinline__ float tanh_f(float x) {
    float e = __builtin_amdgcn_exp2f(x * 2.885390081777927f);
    return fmaf(-2.f, fast_rcp(1.f + e), 1.f);
}
// fp16 hi/lo split: v = hi + lo with |lo| <= ulp(hi)/2 -> W error negligible
__device__ __forceinline__ void hsplit(float x, ushort& hi, ushort& lo) {
    _Float16 h = (_Float16)x;
    _Float16 l = (_Float16)(x - (float)h);
    hi = *(ushort*)&h;
    lo = *(ushort*)&l;
}

// ================= prep0: weight repack =================
__global__ void prep0_kernel(const float* __restrict__ W_ih, const float* __restrict__ W_hh,
                             const float* __restrict__ b_ih, const float* __restrict__ b_hh,
                             const float* __restrict__ lin_l_w, const float* __restrict__ lin_r_w,
                             char* __restrict__ wsb) {
    int i = blockIdx.x * 256 + threadIdx.x;
    float* WTI = (float*)(wsb + OFF_WTI);
    float* BP  = (float*)(wsb + OFF_BP);
    ushort* WHI = (ushort*)(wsb + OFF_WHH_HI);
    ushort* WLO = (ushort*)(wsb + OFF_WHH_LO);
    ushort* LHI = (ushort*)(wsb + OFF_LIN_HI);
    ushort* LLO = (ushort*)(wsb + OFF_LIN_LO);
    float* LRT = (float*)(wsb + OFF_LRT);
    if (i < 65536) {
        int k = i >> 9, p = i & 511;
        WTI[i] = W_ih[((p & 3) * 128 + (p >> 2)) * 128 + k];
    } else if (i < 66048) {
        int p = i - 65536;
        int row = (p & 3) * 128 + (p >> 2);
        BP[p] = b_ih[row] + b_hh[row];
    } else if (i < 131584) {
        int e = i - 66048;
        int frag = e >> 9, lane = (e >> 3) & 63, j = e & 7;
        int mt = frag >> 2, ks = frag & 3;
        int p = mt * 16 + (lane & 15);
        int k = ks * 32 + ((lane >> 4) & 3) * 8 + j;
        float v = W_hh[((p & 3) * 128 + (p >> 2)) * 128 + k];
        ushort hi, lo; hsplit(v, hi, lo);
        WHI[e] = hi; WLO[e] = lo;
    } else if (i < 147968) {
        int e = i - 131584;
        int frag = e >> 9, lane = (e >> 3) & 63, j = e & 7;
        int mt = frag >> 2, ks = frag & 3;
        int row = mt * 16 + (lane & 15);
        int k = ks * 32 + ((lane >> 4) & 3) * 8 + j;
        float v = lin_l_w[row * 128 + k];
        ushort hi, lo; hsplit(v, hi, lo);
        LHI[e] = hi; LLO[e] = lo;
    } else if (i < 164352) {
        int e = i - 147968;
        int k = e >> 7, j = e & 127;
        LRT[e] = lin_r_w[j * 128 + k];
    }
}

// ================= prep_xw: XW = x @ W_ih^T + b (fp16, packed) =================
__global__ __launch_bounds__(256, 2)
void prep_xw_kernel(const float* __restrict__ node_feats, char* __restrict__ wsb) {
    const float* __restrict__ WTI = (const float*)(wsb + OFF_WTI);
    const float* __restrict__ BP  = (const float*)(wsb + OFF_BP);
    __half2* __restrict__ XW = (__half2*)(wsb + OFF_XW);
    __shared__ __align__(16) float xs[32][128];
    const int tid = threadIdx.x;
    const int n0 = blockIdx.x * 32;
    {
        int m = tid >> 3, sub = tid & 7;
        const float4* srow = (const float4*)(node_feats + (size_t)(n0 + m) * CI);
        float4* drow = (float4*)(&xs[m][0]);
        #pragma unroll
        for (int it = 0; it < 4; ++it) drow[sub + it * 8] = srow[sub + it * 8];
    }
    __syncthreads();
    float acc0[32], acc1[32];
    #pragma unroll
    for (int m = 0; m < 32; ++m) { acc0[m] = 0.f; acc1[m] = 0.f; }
    const float* wb = WTI + tid * 2;
    float2 w0 = *(const float2*)(wb + 0 * NG);
    float2 w1 = *(const float2*)(wb + 1 * NG);
    float2 w2 = *(const float2*)(wb + 2 * NG);
    float2 w3 = *(const float2*)(wb + 3 * NG);
    #pragma unroll 1
    for (int c = 0; c < 128; c += 4) {
        const int cn = (c + 4) & 127;
        float2 u0 = *(const float2*)(wb + (cn + 0) * NG);
        float2 u1 = *(const float2*)(wb + (cn + 1) * NG);
        float2 u2 = *(const float2*)(wb + (cn + 2) * NG);
        float2 u3 = *(const float2*)(wb + (cn + 3) * NG);
        #pragma unroll
        for (int m = 0; m < 32; ++m) {
            float4 iv = *(const float4*)(&xs[m][c]);
            acc0[m] = fmaf(iv.x, w0.x, acc0[m]); acc1[m] = fmaf(iv.x, w0.y, acc1[m]);
            acc0[m] = fmaf(iv.y, w1.x, acc0[m]); acc1[m] = fmaf(iv.y, w1.y, acc1[m]);
            acc0[m] = fmaf(iv.z, w2.x, acc0[m]); acc1[m] = fmaf(iv.z, w2.y, acc1[m]);
            acc0[m] = fmaf(iv.w, w3.x, acc0[m]); acc1[m] = fmaf(iv.w, w3.y, acc1[m]);
        }
        w0 = u0; w1 = u1; w2 = u2; w3 = u3;
    }
    const float b0 = BP[tid * 2], b1 = BP[tid * 2 + 1];
    #pragma unroll
    for (int m = 0; m < 32; ++m) {
        __half2 hv = __floats2half2_rn(acc0[m] + b0, acc1[m] + b1);
        XW[(size_t)(n0 + m) * 256 + tid] = hv;
    }
}

// ================= prep_xr: XR = x @ lin_r^T + lin_l_b (fp32) =================
__global__ __launch_bounds__(256, 2)
void prep_xr_kernel(const float* __restrict__ node_feats, const float* __restrict__ lin_l_b,
                    char* __restrict__ wsb) {
    const float* __restrict__ LRT = (const float*)(wsb + OFF_LRT);
    float* __restrict__ XR = (float*)(wsb + OFF_XR);
    __shared__ __align__(16) float xs[32][128];
    const int tid = threadIdx.x;
    const int n0 = blockIdx.x * 32;
    {
        int m = tid >> 3, sub = tid & 7;
        const float4* srow = (const float4*)(node_feats + (size_t)(n0 + m) * CI);
        float4* drow = (float4*)(&xs[m][0]);
        #pragma unroll
        for (int it = 0; it < 4; ++it) drow[sub + it * 8] = srow[sub + it * 8];
    }
    __syncthreads();
    const int j = tid & 127, mh = tid >> 7;
    float facc[16];
    #pragma unroll
    for (int mm = 0; mm < 16; ++mm) facc[mm] = 0.f;
    const float* lb_ = LRT + j;
    #pragma unroll 1
    for (int c = 0; c < 128; c += 4) {
        float l0 = lb_[(c + 0) * 128];
        float l1 = lb_[(c + 1) * 128];
        float l2 = lb_[(c + 2) * 128];
        float l3 = lb_[(c + 3) * 128];
        #pragma unroll
        for (int mm = 0; mm < 16; ++mm) {
            const float4 iv = *(const float4*)(&xs[mh * 16 + mm][c]);
            facc[mm] = fmaf(iv.x, l0, fmaf(iv.y, l1, fmaf(iv.z, l2, fmaf(iv.w, l3, facc[mm]))));
        }
    }
    const float lbv = lin_l_b[j];
    #pragma unroll
    for (int mm = 0; mm < 16; ++mm)
        XR[(size_t)(n0 + mh * 16 + mm) * 128 + j] = facc[mm] + lbv;
}

// ================= main: fused LSTM recurrence + SAGE epilogue (MFMA) =================
// r9: H stored as SINGLE fp16 LDS array (dbuf, 32KB total; was bf16 hi+lo 64KB),
// recurrence via mfma_f32_16x16x32_f16 2-term (Whi@H + Wlo@H; was 3-term bf16).
// Error analysis: fp16-H adds ~1.4e-4/step to gates -- negligible vs the fp16-XW
// quantization that already dominates absmax (0.0156). Per-half GEMM+cell kept
// (fits 128 VGPR); sched_barrier REMOVED so compiler may interleave half0-cell
// (VALU) with half1-GEMM (MFMA) -- m114 co-issue. LDS 36KB -> better residency.
__global__ __launch_bounds__(512, 2)
void lstm_main_kernel(const int* __restrict__ srcg, const char* __restrict__ wsb,
                      float* __restrict__ out) {
    const ushort* __restrict__ xw  = (const ushort*)(wsb + OFF_XW);
    const float*  __restrict__ xr  = (const float*)(wsb + OFF_XR);
    const ushort* __restrict__ whh_hi = (const ushort*)(wsb + OFF_WHH_HI);
    const ushort* __restrict__ whh_lo = (const ushort*)(wsb + OFF_WHH_LO);
    const ushort* __restrict__ lin_hi = (const ushort*)(wsb + OFF_LIN_HI);
    const ushort* __restrict__ lin_lo = (const ushort*)(wsb + OFF_LIN_LO);

    __shared__ __align__(16) ushort H[2][8192];   // [buf][node*128+ch] fp16, XOR-swizzled
    __shared__ int srcb[1024];                    // [t][node]

    const int tid = threadIdx.x;
    const int n0 = blockIdx.x * 64;
    const int wid = tid >> 6, lane = tid & 63;
    const int l15 = lane & 15, l4 = lane >> 4;
    const int swz = (l15 & 7) << 4;

    for (int i = tid; i < 1024; i += 512) {
        int n = i & 63, t = i >> 6;
        int gn = n0 + n; if (gn > NN - 1) gn = NN - 1;
        srcb[t * 64 + n] = srcg[gn * 16 + t];
    }
    __syncthreads();

    float cst[4][4];
    #pragma unroll
    for (int mt = 0; mt < 4; ++mt)
        #pragma unroll
        for (int nt = 0; nt < 4; ++nt) cst[mt][nt] = 0.f;

    // ---- t = 0 peel: h0 = 0 -> gates = XW only; writes H(0) to buf 0 ----
    #pragma unroll
    for (int h = 0; h < 2; ++h) {
        #pragma unroll
        for (int nt = 0; nt < 4; ++nt) {
            const int sn = srcb[0 * 64 + nt * 16 + l15];
            const ushort* rowp = xw + (size_t)sn * 512;
            #pragma unroll
            for (int mp = 0; mp < 2; ++mp) {
                const int mtg = h * 2 + mp;
                uint2 v = *(const uint2*)(rowp + (wid * 16 + mtg * 4 + l4) * 4);
                float2 f01 = __half22float2(*(__half2*)&v.x);
                float2 f23 = __half22float2(*(__half2*)&v.y);
                float cn_ = sigm(f01.x) * tanh_f(f23.x);   // i*g (f-term: c=0)
                cst[mtg][nt] = cn_;
                float hn = sigm(f23.y) * tanh_f(cn_);
                _Float16 hf = (_Float16)hn;
                const int wb = ((nt * 16 + l15) * 256 + (wid * 16 + mtg * 4 + l4) * 2) ^ swz;
                *(ushort*)((char*)H[0] + wb) = *(ushort*)&hf;
            }
        }
    }
    __syncthreads();

    #pragma unroll 1
    for (int t = 1; t < KK; ++t) {
        const char* HR = (const char*)H[(t + 1) & 1];   // read buf (t-1)&1
        char* HW = (char*)H[t & 1];

        #pragma unroll
        for (int h = 0; h < 2; ++h) {
            // --- JIT gather of this half's XW (8 loads, hidden under MFMAs) ---
            uint2 xwv[2][4];
            #pragma unroll
            for (int nt = 0; nt < 4; ++nt) {
                const int sn = srcb[t * 64 + nt * 16 + l15];
                const ushort* rowp = xw + (size_t)sn * 512 + (wid * 16 + l4) * 4;
                #pragma unroll
                for (int mp = 0; mp < 2; ++mp)
                    xwv[mp][nt] = *(const uint2*)(rowp + (h * 2 + mp) * 16);
            }
            // --- GEMM for this half: acc[2][4], 2-term fp16 ---
            f32x4 acc[2][4];
            #pragma unroll
            for (int mp = 0; mp < 2; ++mp)
                #pragma unroll
                for (int nt = 0; nt < 4; ++nt) acc[mp][nt] = (f32x4){0.f, 0.f, 0.f, 0.f};

            #pragma unroll
            for (int ks = 0; ks < 4; ++ks) {
                f16x8 ah[2], al[2];
                #pragma unroll
                for (int mp = 0; mp < 2; ++mp) {
                    const int fo = (((wid * 4 + h * 2 + mp) * 4 + ks) << 9) + lane * 8;
                    ah[mp] = *(const f16x8*)(whh_hi + fo);
                    al[mp] = *(const f16x8*)(whh_lo + fo);
                }
                #pragma unroll
                for (int nt = 0; nt < 4; ++nt) {
                    const int bo = ((nt * 16 + l15) * 256 + ks * 64 + l4 * 16) ^ swz;
                    f16x8 bv = *(const f16x8*)(HR + bo);
                    #pragma unroll
                    for (int mp = 0; mp < 2; ++mp) {
                        acc[mp][nt] = __builtin_amdgcn_mfma_f32_16x16x32_f16(ah[mp], bv, acc[mp][nt], 0, 0, 0);
                        acc[mp][nt] = __builtin_amdgcn_mfma_f32_16x16x32_f16(al[mp], bv, acc[mp][nt], 0, 0, 0);
                    }
                }
            }
            // --- cell for this half's channels; writes H(t) fp16 to write-buf ---
            #pragma unroll
            for (int mp = 0; mp < 2; ++mp) {
                const int mtg = h * 2 + mp;
                #pragma unroll
                for (int nt = 0; nt < 4; ++nt) {
                    uint2 v = xwv[mp][nt];
                    float2 f01 = __half22float2(*(__half2*)&v.x);
                    float2 f23 = __half22float2(*(__half2*)&v.y);
                    float gi = acc[mp][nt][0] + f01.x;
                    float gf = acc[mp][nt][1] + f01.y;
                    float gg = acc[mp][nt][2] + f23.x;
                    float go = acc[mp][nt][3] + f23.y;
                    float cn_ = fmaf(sigm(gi), tanh_f(gg), sigm(gf) * cst[mtg][nt]);
                    cst[mtg][nt] = cn_;
                    float hn = sigm(go) * tanh_f(cn_);
                    _Float16 hf = (_Float16)hn;
                    const int wb = ((nt * 16 + l15) * 256 + (wid * 16 + mtg * 4 + l4) * 2) ^ swz;
                    *(ushort*)(HW + wb) = *(ushort*)&hf;
                }
            }
        }
        __syncthreads();   // H(t) complete; H(t-1) free for overwrite next step
    }

    // ---- epilogue: out = relu(XR + h_last @ lin_l^T), h_last in buf 1 ----
    f32x4 acc2[4];
    #pragma unroll
    for (int nt = 0; nt < 4; ++nt) acc2[nt] = (f32x4){0.f, 0.f, 0.f, 0.f};
    #pragma unroll
    for (int ks = 0; ks < 4; ++ks) {
        const int fo = ((wid * 4 + ks) << 9) + lane * 8;
        f16x8 ah = *(const f16x8*)(lin_hi + fo);
        f16x8 al = *(const f16x8*)(lin_lo + fo);
        #pragma unroll
        for (int nt = 0; nt < 4; ++nt) {
            const int bo = ((nt * 16 + l15) * 256 + ks * 64 + l4 * 16) ^ swz;
            f16x8 bv = *(const f16x8*)((const char*)H[1] + bo);
            acc2[nt] = __builtin_amdgcn_mfma_f32_16x16x32_f16(ah, bv, acc2[nt], 0, 0, 0);
            acc2[nt] = __builtin_amdgcn_mfma_f32_16x16x32_f16(al, bv, acc2[nt], 0, 0, 0);
        }
    }
    #pragma unroll
    for (int nt = 0; nt < 4; ++nt) {
        const int nl = nt * 16 + l15;
        const int gn = n0 + nl;
        if (gn < NN) {
            const size_t base = (size_t)gn * 128 + wid * 16 + l4 * 4;
            float4 xv = *(const float4*)(xr + base);
            float4 ov;
            ov.x = fmaxf(acc2[nt][0] + xv.x, 0.f);
            ov.y = fmaxf(acc2[nt][1] + xv.y, 0.f);
            ov.z = fmaxf(acc2[nt][2] + xv.z, 0.f);
            ov.w = fmaxf(acc2[nt][3] + xv.w, 0.f);
            *(float4*)(out + base) = ov;
        }
    }
}

// ===================== round-1 fallback path (small ws) =====================
__global__ void prep_kernel(const float* __restrict__ W_ih, const float* __restrict__ W_hh,
                            const float* __restrict__ b_ih, const float* __restrict__ b_hh,
                            const float* __restrict__ lin_l_w, const float* __restrict__ lin_r_w,
                            float* __restrict__ ws) {
    int i = blockIdx.x * 256 + threadIdx.x;
    if (i < WT_SZ) {
        int cc = i >> 9, jj = i & 511;
        int ch = jj >> 2, g = jj & 3;
        int row = g * 128 + ch;
        ws[WT_OFF + i] = (cc < 128) ? W_ih[row * 128 + cc] : W_hh[row * 128 + (cc - 128)];
    } else if (i < WT_SZ + LT_SZ) {
        int k = i - WT_SZ;
        int cc = k >> 7, j = k & 127;
        ws[i] = (cc < 128) ? lin_r_w[j * 128 + cc] : lin_l_w[j * 128 + (cc - 128)];
    } else if (i < WS_FLOATS) {
        int j = i - (WT_SZ + LT_SZ);
        int ch = j >> 2, g = j & 3;
        ws[i] = b_ih[g * 128 + ch] + b_hh[g * 128 + ch];
    }
}

__global__ __launch_bounds__(256, 2)
void gnn_lstm_kernel(const float* __restrict__ node_feats,
                     const int* __restrict__ src,
                     const float* __restrict__ lin_l_b,
                     const float* __restrict__ ws,
                     float* __restrict__ out) {
    const float* __restrict__ WT = ws + WT_OFF;
    const float* __restrict__ LT = ws + LT_OFF;
    const float* __restrict__ BP = ws + BP_OFF;
    __shared__ __align__(16) float xh[32][256];
    const int tid = threadIdx.x;
    const int n0 = blockIdx.x * 32;
    {
        int ch = tid >> 1;
        #pragma unroll
        for (int m = 0; m < 32; ++m) xh[m][128 + ch] = 0.f;
    }
    float creg[32];
    #pragma unroll
    for (int m = 0; m < 32; ++m) creg[m] = 0.f;
    const float4 bpv = *(const float4*)(BP + ((tid >> 1) << 2));
    const bool odd = (tid & 1);
    const float* wb = WT + (tid << 1);
    for (int t = 0; t < KK; ++t) {
        {
            int m = tid >> 3, sub = tid & 7;
            int sidx = src[(n0 + m) * KK + t];
            const float4* srow = (const float4*)(node_feats + (size_t)sidx * CI);
            float4* drow = (float4*)(&xh[m][0]);
            #pragma unroll
            for (int it = 0; it < 4; ++it) drow[sub + it * 8] = srow[sub + it * 8];
        }
        __syncthreads();
        float acc0[32], acc1[32];
        #pragma unroll
        for (int m = 0; m < 32; ++m) { acc0[m] = 0.f; acc1[m] = 0.f; }
        float2 w0 = *(const float2*)(wb + 0 * NG);
        float2 w1 = *(const float2*)(wb + 1 * NG);
        float2 w2 = *(const float2*)(wb + 2 * NG);
        float2 w3 = *(const float2*)(wb + 3 * NG);
        #pragma unroll 1
        for (int c = 0; c < 256; c += 4) {
            const int cn = (c + 4) & 255;
            float2 u0 = *(const float2*)(wb + (cn + 0) * NG);
            float2 u1 = *(const float2*)(wb + (cn + 1) * NG);
            float2 u2 = *(const float2*)(wb + (cn + 2) * NG);
            float2 u3 = *(const float2*)(wb + (cn + 3) * NG);
            #pragma unroll
            for (int m = 0; m < 32; ++m) {
                float4 iv = *(const float4*)(&xh[m][c]);
                acc0[m] = fmaf(iv.x, w0.x, acc0[m]); acc1[m] = fmaf(iv.x, w0.y, acc1[m]);
                acc0[m] = fmaf(iv.y, w1.x, acc0[m]); acc1[m] = fmaf(iv.y, w1.y, acc1[m]);
                acc0[m] = fmaf(iv.z, w2.x, acc0[m]); acc1[m] = fmaf(iv.z, w2.y, acc1[m]);
                acc0[m] = fmaf(iv.w, w3.x, acc0[m]); acc1[m] = fmaf(iv.w, w3.y, acc1[m]);
            }
            w0 = u0; w1 = u1; w2 = u2; w3 = u3;
        }
        __syncthreads();
        const int ch = tid >> 1;
        #pragma unroll
        for (int m = 0; m < 32; ++m) {
            float a0 = acc0[m], a1 = acc1[m];
            float p0 = __shfl_xor(a0, 1);
            float p1 = __shfl_xor(a1, 1);
            float gi = (odd ? p0 : a0) + bpv.x;
            float gf = (odd ? p1 : a1) + bpv.y;
            float gg = (odd ? a0 : p0) + bpv.z;
            float go = (odd ? a1 : p1) + bpv.w;
            float cn_ = sigm(gf) * creg[m] + sigm(gi) * tanh_f(gg);
            creg[m] = cn_;
            float hn = sigm(go) * tanh_f(cn_);
            xh[m][128 + ch] = hn;
        }
    }
    {
        int m = tid >> 3, sub = tid & 7;
        const float4* srow = (const float4*)(node_feats + (size_t)(n0 + m) * CI);
        float4* drow = (float4*)(&xh[m][0]);
        #pragma unroll
        for (int it = 0; it < 4; ++it) drow[sub + it * 8] = srow[sub + it * 8];
    }
    __syncthreads();
    {
        const int jo = tid & 127;
        const int mh = tid >> 7;
        float facc[16];
        #pragma unroll
        for (int mm = 0; mm < 16; ++mm) facc[mm] = 0.f;
        const float* lb_ = LT + jo;
        #pragma unroll 1
        for (int c = 0; c < 256; c += 4) {
            float l0 = lb_[(c + 0) * 128];
            float l1 = lb_[(c + 1) * 128];
            float l2 = lb_[(c + 2) * 128];
            float l3 = lb_[(c + 3) * 128];
            #pragma unroll
            for (int mm = 0; mm < 16; ++mm) {
                const float4 iv = *(const float4*)(&xh[mh * 16 + mm][c]);
                facc[mm] = fmaf(iv.x, l0, fmaf(iv.y, l1, fmaf(iv.z, l2, fmaf(iv.w, l3, facc[mm]))));
            }
        }
        const float lbv = lin_l_b[jo];
        #pragma unroll
        for (int mm = 0; mm < 16; ++mm) {
            float v = facc[mm] + lbv;
            out[(size_t)(n0 + mh * 16 + mm) * CI + jo] = fmaxf(v, 0.f);
        }
    }
}

extern "C" void kernel_launch(void* const* d_in, const int* in_sizes, int n_in,
                              void* d_out, int out_size, void* d_ws, size_t ws_size,
                              hipStream_t stream) {
    const float* node_feats = (const float*)d_in[0];
    const int*   edge_index = (const int*)d_in[1];
    const float* W_ih    = (const float*)d_in[2];
    const float* W_hh    = (const float*)d_in[3];
    const float* b_ih    = (const float*)d_in[4];
    const float* b_hh    = (const float*)d_in[5];
    const float* lin_l_w = (const float*)d_in[6];
    const float* lin_l_b = (const float*)d_in[7];
    const float* lin_r_w = (const float*)d_in[8];
    const int* src = edge_index;
    float* outp = (float*)d_out;

    if (ws_size >= WS_NEED) {
        char* wsb = (char*)d_ws;
        hipLaunchKernelGGL(prep0_kernel, dim3(642), dim3(256), 0, stream,
                           W_ih, W_hh, b_ih, b_hh, lin_l_w, lin_r_w, wsb);
        hipLaunchKernelGGL(prep_xw_kernel, dim3(3125), dim3(256), 0, stream, node_feats, wsb);
        hipLaunchKernelGGL(prep_xr_kernel, dim3(3125), dim3(256), 0, stream, node_feats, lin_l_b, wsb);
        hipLaunchKernelGGL(lstm_main_kernel, dim3((NN + 63) / 64), dim3(512), 0, stream,
                           src, wsb, outp);
    } else {
        float* ws = (float*)d_ws;
        hipLaunchKernelGGL(prep_kernel, dim3((WS_FLOATS + 255) / 256), dim3(256), 0, stream,
                           W_ih, W_hh, b_ih, b_hh, lin_l_w, lin_r_w, ws);
        hipLaunchKernelGGL(gnn_lstm_kernel, dim3(NN / 32), dim3(256), 0, stream,
                           node_feats, src, lin_l_b, ws, outp);
    }
}